// Round 13
// baseline (413.240 us; speedup 1.0000x reference)
//
#include <hip/hip_runtime.h>
#include <stdint.h>

#define S_LEN 2048
#define DHEAD 64
#define BATCH 4
#define HEADS 16
#define QBLK 16
#define KBLK 128
#define NT 16                 // S_LEN / KBLK
#define NBLK 8192             // 64 bh * 128 q-tiles
#define NEG_BIG (-1e9f)

typedef _Float16 half4v __attribute__((ext_vector_type(4)));
typedef _Float16 half8v __attribute__((ext_vector_type(8)));
typedef float floatx4 __attribute__((ext_vector_type(4)));

// d_ws layout (bytes): qh 16MB | kh 16MB | vt 16MB | bm 2MB
#define QH_OFF 0u
#define KH_OFF 16777216u
#define VT_OFF 33554432u
#define BM_OFF 50331648u

#define WAITV(N) asm volatile("s_waitcnt vmcnt(" #N ")" ::: "memory")
#define WAITL()  asm volatile("s_waitcnt lgkmcnt(0)" ::: "memory")
#define FENCE()  asm volatile("" ::: "memory")
#define BAR()    __builtin_amdgcn_s_barrier()

__device__ __forceinline__ void glds16(const void* g, void* l) {
    __builtin_amdgcn_global_load_lds(
        (const __attribute__((address_space(1))) uint32_t*)g,
        (__attribute__((address_space(3))) uint32_t*)(uint32_t)(uintptr_t)l,
        16, 0, 0);
}

// ---------------- pre-pass 1: q,k -> f16 (q pre-scaled by 1/8) ----------------
__global__ __launch_bounds__(256) void prep_qk(const float* __restrict__ q, const float* __restrict__ k,
                                               _Float16* __restrict__ qh, _Float16* __restrict__ kh) {
    int i = blockIdx.x * 256 + threadIdx.x;
    const float* src; _Float16* dst; float s;
    if (i < 1048576) { src = q + (size_t)i * 8; dst = qh + (size_t)i * 8; s = 0.125f; }
    else { int j = i - 1048576; src = k + (size_t)j * 8; dst = kh + (size_t)j * 8; s = 1.0f; }
    floatx4 a = *(const floatx4*)src;
    floatx4 b = *(const floatx4*)(src + 4);
    half8v h;
    h[0]=(_Float16)(a[0]*s); h[1]=(_Float16)(a[1]*s); h[2]=(_Float16)(a[2]*s); h[3]=(_Float16)(a[3]*s);
    h[4]=(_Float16)(b[0]*s); h[5]=(_Float16)(b[1]*s); h[6]=(_Float16)(b[2]*s); h[7]=(_Float16)(b[3]*s);
    *(half8v*)dst = h;
}

// ---------------- pre-pass 2: v -> f16 transposed vt[bh][d][s] (LDS transpose) ----------------
__global__ __launch_bounds__(256) void prep_vt(const float* __restrict__ v, _Float16* __restrict__ vt) {
    __shared__ _Float16 lt[64][72];
    int bh = blockIdx.x >> 5;
    int s0 = (blockIdx.x & 31) * 64;
    int t  = threadIdx.x;
    {
        int row = t >> 2, dq = t & 3;
        const float* vb = v + ((size_t)bh * S_LEN + s0 + row) * DHEAD + dq * 16;
        #pragma unroll
        for (int q = 0; q < 4; ++q) {
            floatx4 val = *(const floatx4*)(vb + q * 4);
            #pragma unroll
            for (int j = 0; j < 4; ++j) lt[dq * 16 + q * 4 + j][row] = (_Float16)val[j];
        }
    }
    __syncthreads();
    {
        int d = t >> 2, kq = t & 3;
        half8v h0 = *(const half8v*)&lt[d][kq * 16];
        half8v h1 = *(const half8v*)&lt[d][kq * 16 + 8];
        _Float16* dst = vt + (size_t)bh * DHEAD * S_LEN + (size_t)d * S_LEN + s0 + kq * 16;
        *(half8v*)dst = h0;
        *(half8v*)(dst + 8) = h1;
    }
}

// ---------------- pre-pass 3: mask -> bitmask (u64 per 64 keys) ----------------
__global__ __launch_bounds__(256) void prep_bm(const int* __restrict__ mask, unsigned long long* __restrict__ bm) {
    int lane = threadIdx.x & 63, w = threadIdx.x >> 6;
    size_t row = (size_t)blockIdx.x * 4 + w;
    const int* mrow = mask + row * S_LEN;
    unsigned long long* brow = bm + row * 32;
    #pragma unroll 4
    for (int t = 0; t < 32; ++t) {
        unsigned long long bits = __ballot(mrow[t * 64 + lane] != 0);
        if (lane == 0) brow[t] = bits;
    }
}

// ---------------- main: single-pass flash, unnormalized P in regs, deferred attn store ----------------
__global__ __launch_bounds__(512, 4)
void attn_main(const _Float16* __restrict__ qh, const _Float16* __restrict__ kh,
               const _Float16* __restrict__ vt, const uint32_t* __restrict__ bm,
               float* __restrict__ outg, float* __restrict__ attng)
{
    __shared__ __attribute__((aligned(16))) char smem[70144];
    char* kbuf = smem;                       // [2][16384] K[key][d], quad-swizzled
    char* vbuf = smem + 32768;               // [2][16384] Vt[d][key], quad-swizzled
    char* pb   = smem + 65536;               // [4096] P[16 rows][128 keys] f16, quad-swizzled
    float* zbf = (float*)(smem + 69632);     // [8][16]

    const int tid  = threadIdx.x;
    const int lane = tid & 63;
    const int w    = tid >> 6;    // 0..7: QK key-chunk; PV (kc2 = w&3, dc = w>>2)
    const int c    = lane & 15;
    const int g    = lane >> 4;
    const int kc2  = w & 3;
    const int dc   = w >> 2;

    const int raw = blockIdx.x;
    const int lb  = (raw & 7) * (NBLK / 8) + (raw >> 3);
    const int bh  = lb >> 7;              // 128 q-tiles per (b,h)
    const int q0  = (lb & 127) * QBLK;
    const int bb  = bh >> 4;

    const _Float16* qp = qh + (size_t)bh * S_LEN * DHEAD;
    const char* kpc = (const char*)(kh + (size_t)bh * S_LEN * DHEAD);
    const char* vpc = (const char*)(vt + (size_t)bh * DHEAD * S_LEN);
    float* outp  = outg  + (size_t)bh * S_LEN * DHEAD;
    float* attnp = attng + (size_t)bh * S_LEN * S_LEN;

    // ---- staging sources (pre-swizzled global, linear LDS dest — rule 21) ----
    const int ksrow = tid >> 3;                         // key 0..63 (half A); +64 half B
    const char* ksrcA = kpc + ksrow * 128 + (((tid & 7) ^ (ksrow & 7)) << 4);   // + t*16384; B +8192
    const int vsd = tid >> 4;                           // d 0..31 (half A); +32 half B
    const int vswz = ((tid & 15) ^ (vsd & 15)) << 4;    // (32+vsd)&15 == vsd&15
    const char* vsrcA = vpc + vsd * 4096 + vswz;        // + t*256
    const char* vsrcB = vpc + (32 + vsd) * 4096 + vswz;

    // ---- Q A-frags: rows q0+c, k(d) = g*8+j (+32) ----
    half8v qf0, qf1;
    {
        const _Float16* qb = qp + (size_t)(q0 + c) * DHEAD + g * 8;
        qf0 = *(const half8v*)qb;
        qf1 = *(const half8v*)(qb + 32);
    }

    // ---- K B-frag offsets: key kk = w*16+c, quads g / 4+g (XOR kk&7) ----
    const int kk = w * 16 + c;
    const int koff0 = kk * 128 + ((g ^ (kk & 7)) << 4);
    const int koff1 = kk * 128 + (((4 + g) ^ (kk & 7)) << 4);

    // ---- V B-frag offsets: rows d = dc*32+c / +16, quad kc2*4+g (XOR d&15) ----
    const int vd0 = dc * 32 + c, vd1 = vd0 + 16;
    const int voff0 = vd0 * 256 + (((kc2 * 4 + g) ^ (vd0 & 15)) << 4);
    const int voff1 = vd1 * 256 + (((kc2 * 4 + g) ^ (vd1 & 15)) << 4);

    // ---- pb addressing (16 rows x 128 keys f16, 16-quad XOR swizzle) ----
    const int q8 = kk >> 3;
    int pwo0, pwo1, pwo2, pwo3;
    {
        int r0 = g * 4;
        pwo0 = (r0 + 0) * 256 + (((q8 ^ (r0 + 0)) & 15) << 4) + (kk & 7) * 2;
        pwo1 = (r0 + 1) * 256 + (((q8 ^ (r0 + 1)) & 15) << 4) + (kk & 7) * 2;
        pwo2 = (r0 + 2) * 256 + (((q8 ^ (r0 + 2)) & 15) << 4) + (kk & 7) * 2;
        pwo3 = (r0 + 3) * 256 + (((q8 ^ (r0 + 3)) & 15) << 4) + (kk & 7) * 2;
    }
    const int poff = c * 256 + (((kc2 * 4 + g) ^ c) << 4);          // PV A-frag (b128)
    const int srr  = tid >> 5, sk4 = tid & 31;                       // store-loop mapping
    const int proff = srr * 256 + ((((sk4 >> 1) ^ srr) & 15) << 4) + (sk4 & 1) * 8;
    float* abase = attnp + (size_t)(q0 + srr) * S_LEN + sk4 * 4;     // + t*KBLK

    // ---- bitmask: rows q0+g*4+i, u32 idx = t*4 + (w>>1), bit (w&1)*16+c ----
    const uint32_t* bmb = bm + ((size_t)bb * S_LEN + q0 + g * 4) * 64 + (w >> 1);
    const int bmsh = (w & 1) * 16 + c;

    // ======================= single pass: z, p (unnorm, regs), PV (unnorm) =======================
    half4v p[NT];
    float z0 = 0.f, z1 = 0.f, z2 = 0.f, z3 = 0.f;
    floatx4 o0 = {0.f, 0.f, 0.f, 0.f}, o1 = o0;
    uint32_t bc0, bc1, bc2, bc3, bn0, bn1, bn2, bn3;

    {   // prologue: stage tile 0 + bm(0)
        char* kd = kbuf + tid * 16;
        char* vd = vbuf + tid * 16;
        glds16(ksrcA, kd); glds16(ksrcA + 8192, kd + 8192);
        glds16(vsrcA, vd); glds16(vsrcB, vd + 8192);
        FENCE();
        bc0 = bmb[0]; bc1 = bmb[64]; bc2 = bmb[128]; bc3 = bmb[192];
        FENCE();
    }
    #pragma unroll
    for (int t = 0; t < NT; ++t) {
        BAR(); FENCE();                               // A: buf[(t+1)&1] reads + pb reads done
        if (t + 1 < NT) {
            const char* s = ksrcA + (t + 1) * 16384;
            char* kd = kbuf + (((t + 1) & 1) << 14) + tid * 16;
            glds16(s, kd); glds16(s + 8192, kd + 8192);
            char* vd = vbuf + (((t + 1) & 1) << 14) + tid * 16;
            glds16(vsrcA + (t + 1) * 256, vd);
            glds16(vsrcB + (t + 1) * 256, vd + 8192);
            FENCE();
            int i4 = (t + 1) * 4;
            bn0 = bmb[i4]; bn1 = bmb[64 + i4]; bn2 = bmb[128 + i4]; bn3 = bmb[192 + i4];
            WAITV(8);                                 // tile t's 4 glds (+older) drained
        } else { WAITV(0); }
        BAR(); FENCE();                               // B: tile t visible
        const char* kbB = kbuf + ((t & 1) << 14);
        const char* vbB = vbuf + ((t & 1) << 14);
        half8v kf0 = *(const half8v*)(kbB + koff0);
        half8v kf1 = *(const half8v*)(kbB + koff1);
        floatx4 acc = {0.f, 0.f, 0.f, 0.f};
        acc = __builtin_amdgcn_mfma_f32_16x16x32_f16(qf0, kf0, acc, 0, 0, 0);
        acc = __builtin_amdgcn_mfma_f32_16x16x32_f16(qf1, kf1, acc, 0, 0, 0);
        float e0 = __expf(((bc0 >> bmsh) & 1u) ? acc[0] : NEG_BIG);
        float e1 = __expf(((bc1 >> bmsh) & 1u) ? acc[1] : NEG_BIG);
        float e2 = __expf(((bc2 >> bmsh) & 1u) ? acc[2] : NEG_BIG);
        float e3 = __expf(((bc3 >> bmsh) & 1u) ? acc[3] : NEG_BIG);
        z0 += e0; z1 += e1; z2 += e2; z3 += e3;
        bc0 = bn0; bc1 = bn1; bc2 = bn2; bc3 = bn3;
        half4v ph; ph[0] = (_Float16)e0; ph[1] = (_Float16)e1;
        ph[2] = (_Float16)e2; ph[3] = (_Float16)e3;
        p[t] = ph;                                    // keep unnormalized P (static index)
        *(_Float16*)(pb + pwo0) = ph[0];
        *(_Float16*)(pb + pwo1) = ph[1];
        *(_Float16*)(pb + pwo2) = ph[2];
        *(_Float16*)(pb + pwo3) = ph[3];
        WAITL(); BAR(); FENCE();                      // C: p visible
        half8v af  = *(const half8v*)(pb + poff);     // P rows, keys kc2*32+g*8..
        half8v vf0 = *(const half8v*)(vbB + voff0);
        half8v vf1 = *(const half8v*)(vbB + voff1);
        o0 = __builtin_amdgcn_mfma_f32_16x16x32_f16(af, vf0, o0, 0, 0, 0);
        o1 = __builtin_amdgcn_mfma_f32_16x16x32_f16(af, vf1, o1, 0, 0, 0);
    }

    // ---- finalize z -> r (rows g*4+i) ----
    #pragma unroll
    for (int off = 1; off <= 8; off <<= 1) {
        z0 += __shfl_xor(z0, off); z1 += __shfl_xor(z1, off);
        z2 += __shfl_xor(z2, off); z3 += __shfl_xor(z3, off);
    }
    if (c == 0) {
        zbf[w * 16 + g * 4 + 0] = z0; zbf[w * 16 + g * 4 + 1] = z1;
        zbf[w * 16 + g * 4 + 2] = z2; zbf[w * 16 + g * 4 + 3] = z3;
    }
    WAITL(); BAR(); FENCE();
    float r0_, r1_, r2_, r3_;
    {
        float s0 = 0.f, s1 = 0.f, s2 = 0.f, s3 = 0.f;
        #pragma unroll
        for (int ww = 0; ww < 8; ++ww) {
            s0 += zbf[ww * 16 + g * 4 + 0]; s1 += zbf[ww * 16 + g * 4 + 1];
            s2 += zbf[ww * 16 + g * 4 + 2]; s3 += zbf[ww * 16 + g * 4 + 3];
        }
        r0_ = 1.f / s0; r1_ = 1.f / s1; r2_ = 1.f / s2; r3_ = 1.f / s3;
    }
    // rescale O by r (rows g*4+i)
    o0[0] *= r0_; o0[1] *= r1_; o0[2] *= r2_; o0[3] *= r3_;
    o1[0] *= r0_; o1[1] *= r1_; o1[2] *= r2_; o1[3] *= r3_;

    // ======================= deferred attn store: p[t]*r via pb, line-complete =======================
    #pragma unroll
    for (int t = 0; t < NT; ++t) {
        BAR(); FENCE();                               // pb free
        half4v ph = p[t];
        *(_Float16*)(pb + pwo0) = (_Float16)((float)ph[0] * r0_);
        *(_Float16*)(pb + pwo1) = (_Float16)((float)ph[1] * r1_);
        *(_Float16*)(pb + pwo2) = (_Float16)((float)ph[2] * r2_);
        *(_Float16*)(pb + pwo3) = (_Float16)((float)ph[3] * r3_);
        WAITL(); BAR(); FENCE();                      // p*r visible
        half4v pv4 = *(const half4v*)(pb + proff);
        floatx4 st = {(float)pv4[0], (float)pv4[1], (float)pv4[2], (float)pv4[3]};
        __builtin_nontemporal_store(st, (floatx4*)(abase + t * KBLK));
    }

    // ======================= out: kc2-reduction + coalesced store =======================
    BAR(); FENCE();                                   // pb reads done; kbuf/vbuf dead
    float* rbuf = (float*)smem;                       // [8][16][33]
    {
        int base = w * 528 + (g * 4) * 33 + c;
        rbuf[base]           = o0[0]; rbuf[base + 33]      = o0[1];
        rbuf[base + 66]      = o0[2]; rbuf[base + 99]      = o0[3];
        rbuf[base + 16]      = o1[0]; rbuf[base + 33 + 16] = o1[1];
        rbuf[base + 66 + 16] = o1[2]; rbuf[base + 99 + 16] = o1[3];
    }
    WAITL(); BAR(); FENCE();
    {
        int r_ = tid >> 5, d2 = (tid & 31) * 2;
        int dcc = d2 >> 5;
        float v0 = 0.f, v1 = 0.f;
        #pragma unroll
        for (int k2 = 0; k2 < 4; ++k2) {
            int base = (dcc * 4 + k2) * 528 + r_ * 33 + (d2 & 31);
            v0 += rbuf[base]; v1 += rbuf[base + 1];
        }
        float2 st = make_float2(v0, v1);
        *(float2*)(outp + (size_t)(q0 + r_) * DHEAD + d2) = st;
    }
}

extern "C" void kernel_launch(void* const* d_in, const int* in_sizes, int n_in,
                              void* d_out, int out_size, void* d_ws, size_t ws_size,
                              hipStream_t stream) {
    const float* q    = (const float*)d_in[0];
    const float* k    = (const float*)d_in[1];
    const float* v    = (const float*)d_in[2];
    const int*   mask = (const int*)d_in[3];
    float* out  = (float*)d_out;
    float* attn = out + (size_t)BATCH * HEADS * S_LEN * DHEAD;   // tuple: (out, attn)

    char* ws = (char*)d_ws;
    _Float16* qhw = (_Float16*)(ws + QH_OFF);
    _Float16* khw = (_Float16*)(ws + KH_OFF);
    _Float16* vtw = (_Float16*)(ws + VT_OFF);
    unsigned long long* bmw = (unsigned long long*)(ws + BM_OFF);

    prep_qk<<<dim3(8192), dim3(256), 0, stream>>>(q, k, qhw, khw);
    prep_vt<<<dim3(2048), dim3(256), 0, stream>>>(v, vtw);
    prep_bm<<<dim3(2048), dim3(256), 0, stream>>>(mask, bmw);
    attn_main<<<dim3(NBLK), dim3(512), 0, stream>>>(qhw, khw, vtw, (const uint32_t*)bmw, out, attn);
}